// Round 19
// baseline (265.830 us; speedup 1.0000x reference)
//
#include <hip/hip_runtime.h>
#include <hip/hip_bf16.h>
#include <math.h>

#define NA 16384
#define NE 65536
#define AD 29

typedef __attribute__((ext_vector_type(8))) short bfrag8;
typedef __attribute__((ext_vector_type(4))) float f32x4;

__device__ __forceinline__ float sigmoidf_(float x) { return 1.0f / (1.0f + expf(-x)); }
__device__ __forceinline__ unsigned short bf16bits(float x) {
  __hip_bfloat16 hb = __float2bfloat16(x);
  return *reinterpret_cast<unsigned short*>(&hb);
}
__device__ __forceinline__ float bf16val(unsigned short u) {
  unsigned int b = ((unsigned int)u) << 16;
  return __uint_as_float(b);
}

// ============ init h + zero count + ALL weight-fragment preps (one kernel) ====
__global__ void k_init_prep(
    const float* __restrict__ af, float* __restrict__ h, int* __restrict__ count,
    const float* __restrict__ kern, const float* __restrict__ kbias,
    const float* __restrict__ wih, const float* __restrict__ whh,
    const float* __restrict__ w1, const float* __restrict__ w2,
    const float* __restrict__ ipw, const float* __restrict__ opw,
    unsigned short* __restrict__ KrA,
    unsigned short* __restrict__ Wh, unsigned short* __restrict__ Wl,
    unsigned short* __restrict__ W1h, unsigned short* __restrict__ W1l,
    unsigned short* __restrict__ W2h, unsigned short* __restrict__ W2l,
    unsigned short* __restrict__ PQh, unsigned short* __restrict__ PQl,
    unsigned short* __restrict__ POh, unsigned short* __restrict__ POl) {
  int idx0 = blockIdx.x * 256 + threadIdx.x;
  if (idx0 >= NA * 64) return;
  if (idx0 < NA) count[idx0] = 0;
  {
    int a = idx0 >> 6, d = idx0 & 63;
    h[idx0] = (d < AD) ? af[a * AD + d] : 0.0f;
  }
  if (idx0 < 36864) {                     // KrA (message kernel, bf16 single)
    int idx = idx0;
    int r = idx & 7;
    int lane = (idx >> 3) & 63;
    int tmp2 = idx >> 9;                  // ic*18 + ks
    int ks = tmp2 % 18, w = tmp2 / 18;
    int i = w * 16 + (lane & 15);
    int kj = ks * 32 + ((lane >> 4) << 3) + r;
    int k9 = kj >> 6, j = kj & 63;
    float v = (k9 < 8) ? kern[k9 * 4096 + i * 64 + j] : kbias[i * 64 + j];
    KrA[idx] = bf16bits(v);
  } else if (idx0 < 61440) {              // GRU weights hi/lo
    int idx = idx0 - 36864;
    int r = idx & 7;
    int lane = (idx >> 3) & 63;
    int t2 = idx >> 9;
    int ks = t2 & 1;
    int t3 = t2 >> 1;
    int q = t3 % 6, w = t3 / 6;
    int s = q / 3, g = q % 3;
    int R = g * 64 + w * 16 + (lane & 15);
    int kk = ks * 32 + ((lane >> 4) << 3) + r;
    float v = (s == 0) ? wih[R * 64 + kk] : whh[R * 64 + kk];
    unsigned short hi = bf16bits(v);
    Wh[idx] = hi;
    Wl[idx] = bf16bits(v - bf16val(hi));
  } else if (idx0 < 126976) {             // FFN weights hi/lo
    int idx = idx0 - 61440;
    int r = idx & 7;
    int lane = (idx >> 3) & 63;
    int rest = (idx >> 9) & 63;
    if (idx < 32768) {                    // W1
      int tile = rest >> 1, ks = rest & 1;
      int hid = tile * 16 + (lane & 15);
      int kk = ks * 32 + ((lane >> 4) << 3) + r;
      float v = w1[kk * 512 + hid];
      unsigned short hi = bf16bits(v);
      W1h[idx] = hi;
      W1l[idx] = bf16bits(v - bf16val(hi));
    } else {                              // W2
      int i2 = idx - 32768;
      int tile = rest >> 4, ks = rest & 15;
      int outr = tile * 16 + (lane & 15);
      int kk = ks * 32 + ((lane >> 4) << 3) + r;
      float v = w2[kk * 64 + outr];
      unsigned short hi = bf16bits(v);
      W2h[i2] = hi;
      W2l[i2] = bf16bits(v - bf16val(hi));
    }
  } else if (idx0 < 143360) {             // attn in_proj / out_proj hi/lo
    int i = idx0 - 126976;
    if (i < 12288) {                      // ipw: 12 tiles x 2 ksteps
      int r = i & 7;
      int lane = (i >> 3) & 63;
      int rest = i >> 9;                  // 0..23
      int t = rest >> 1, ks = rest & 1;
      int R = t * 16 + (lane & 15);
      int kk = ks * 32 + ((lane >> 4) << 3) + r;
      float v = ipw[R * 64 + kk];
      unsigned short hi = bf16bits(v);
      PQh[i] = hi;
      PQl[i] = bf16bits(v - bf16val(hi));
    } else {                              // opw: 4 tiles x 2 ksteps
      int i2 = i - 12288;
      int r = i2 & 7;
      int lane = (i2 >> 3) & 63;
      int rest = i2 >> 9;                 // 0..7
      int t = rest >> 1, ks = rest & 1;
      int R = t * 16 + (lane & 15);
      int kk = ks * 32 + ((lane >> 4) << 3) + r;
      float v = opw[R * 64 + kk];
      unsigned short hi = bf16bits(v);
      POh[i2] = hi;
      POl[i2] = bf16bits(v - bf16val(hi));
    }
  }
}

// ============ edge bucketing by src (once per call; counting sort) ============
__global__ void k_count(const int* __restrict__ pairs, int* __restrict__ count) {
  int e = blockIdx.x * 256 + threadIdx.x;
  if (e >= NE) return;
  atomicAdd(&count[pairs[2 * e]], 1);
}
__global__ void k_scan1(const int* __restrict__ count, int* __restrict__ bsum) {
  __shared__ int red[256];
  int b = blockIdx.x, t = threadIdx.x;
  red[t] = count[b * 256 + t];
  __syncthreads();
  for (int s = 128; s > 0; s >>= 1) { if (t < s) red[t] += red[t + s]; __syncthreads(); }
  if (t == 0) bsum[b] = red[0];
}
__global__ void k_scan2(const int* __restrict__ count, const int* __restrict__ bsum,
                        int* __restrict__ start, int* __restrict__ cursor) {
  __shared__ int sc[256];
  __shared__ int basev;
  int b = blockIdx.x, t = threadIdx.x;
  if (t < 64) {
    int v = (t < b) ? bsum[t] : 0;
#pragma unroll
    for (int off = 1; off < 64; off <<= 1) v += __shfl_xor(v, off, 64);
    if (t == 0) basev = v;
  }
  int v = count[b * 256 + t];
  sc[t] = v;
  __syncthreads();
  for (int off = 1; off < 256; off <<= 1) {
    int add = (t >= off) ? sc[t - off] : 0;
    __syncthreads();
    sc[t] += add;
    __syncthreads();
  }
  int excl = sc[t] - v + basev;
  start[b * 256 + t] = excl;
  cursor[b * 256 + t] = excl;
  if (b * 256 + t == NA - 1) start[NA] = excl + v;   // sentinel = NE
}
// place + payload reorder fused: write sorted dst + bond features directly.
__global__ void k_place(const int* __restrict__ pairs, int* __restrict__ cursor,
                        const float* __restrict__ bf, int* __restrict__ sdst,
                        float* __restrict__ sbf) {
  int e = blockIdx.x * 256 + threadIdx.x;
  if (e >= NE) return;
  int src = pairs[2 * e], dst = pairs[2 * e + 1];
  int pos = atomicAdd(&cursor[src], 1);
  sdst[pos] = dst;
  const float4* b4 = reinterpret_cast<const float4*>(&bf[e * 8]);
  float4* s4 = reinterpret_cast<float4*>(&sbf[(size_t)pos * 8]);
  s4[0] = b4[0];
  s4[1] = b4[1];
}

// ============ ALL 4 MP steps fused: 1 block = 1 molecule (64 atoms) ============
// Edges are intra-molecule (pair = [mol*64+a, mol*64+b]) so the 4-step loop
// runs entirely in-block: h stays in LDS, gathers are ds_reads, 2 barriers/step.
// ROUND-17 SPILL FIX: outer loops (phase-A g, phase-B/C ic) are `unroll 1` so
// per-thread live state matches k_msg's one-iteration footprint (~100 VGPR);
// round 17's full unroll blew the 256-VGPR cap and spilled 69 MB/dispatch.
__global__ __launch_bounds__(256, 1) void k_mp(
    const float* __restrict__ h_in, const int* __restrict__ start,
    const int* __restrict__ sdst, const float* __restrict__ sbf,
    const unsigned short* __restrict__ KrA,
    const unsigned short* __restrict__ Wh, const unsigned short* __restrict__ Wl,
    const float* __restrict__ bih, const float* __restrict__ bhh,
    float* __restrict__ h_out) {
  __shared__ __align__(16) unsigned short Tb[64 * 584];   // 74,752 B (AHa aliased)
  __shared__ __align__(16) unsigned short Xh[64 * 136];   // 17,408 B
  __shared__ __align__(16) unsigned short Xl[64 * 136];   // 17,408 B
  __shared__ __align__(16) float Hf[64 * 68];             // 17,408 B
  float* AHa = reinterpret_cast<float*>(Tb);              // alias (phase C only)
  const int tid = threadIdx.x, lane = tid & 63, wv = tid >> 6;
  const int mol = blockIdx.x;
  const int molbase = mol * 64;

  // ---- stage h once (fp32 + bf16 hi/lo) ----
#pragma unroll 1
  for (int aa = 0; aa < 16; ++aa) {
    const int a = wv * 16 + aa;
    const float v = h_in[(molbase + a) * 64 + lane];
    Hf[a * 68 + lane] = v;
    const unsigned short hi = bf16bits(v);
    Xh[a * 136 + 64 + lane] = hi;
    Xl[a * 136 + 64 + lane] = bf16bits(v - bf16val(hi));
  }
  // wave's 17 run boundaries (atoms wv*16 .. wv*16+16)
  const int bb = (lane <= 16) ? start[molbase + wv * 16 + lane] : 0;
  __syncthreads();

  const bfrag8* KrA8 = reinterpret_cast<const bfrag8*>(KrA);
  const bfrag8* Wh8 = reinterpret_cast<const bfrag8*>(Wh);
  const bfrag8* Wl8 = reinterpret_cast<const bfrag8*>(Wl);
  const int atomg = wv * 16 + (lane & 15);     // wave's atom for MFMA cols

#pragma unroll 1
  for (int step = 0; step < 4; ++step) {
    // ---- Phase A: gather from LDS h, 4 atoms per g-iter (NOT unrolled) ----
#pragma unroll 1
    for (int g = 0; g < 4; ++g) {
      int s0[4], s1[4];
#pragma unroll
      for (int aa = 0; aa < 4; ++aa) {
        s0[aa] = __shfl(bb, g * 4 + aa, 64);
        s1[aa] = __shfl(bb, g * 4 + aa + 1, 64);
      }
      float t[4][9];
#pragma unroll
      for (int aa = 0; aa < 4; ++aa)
#pragma unroll
        for (int k = 0; k < 9; ++k) t[aa][k] = 0.f;
      float hv[4][8];
#pragma unroll
      for (int aa = 0; aa < 4; ++aa) {
        const int cnt = s1[aa] - s0[aa];
#pragma unroll
        for (int i = 0; i < 8; ++i) {
          hv[aa][i] = 0.f;
          if (i < cnt) {
            int dloc = sdst[s0[aa] + i] - molbase;
            hv[aa][i] = Hf[dloc * 68 + lane];
          }
        }
      }
#pragma unroll
      for (int aa = 0; aa < 4; ++aa) {
        const int cnt = s1[aa] - s0[aa];
#pragma unroll
        for (int i = 0; i < 8; ++i) {
          if (i < cnt) {
#pragma unroll
            for (int k = 0; k < 8; ++k)
              t[aa][k] = fmaf(sbf[(size_t)(s0[aa] + i) * 8 + k], hv[aa][i], t[aa][k]);
            t[aa][8] += hv[aa][i];
          }
        }
      }
      // leftovers (>8 edges on an atom; rare)
#pragma unroll 1
      for (int aa = 0; aa < 4; ++aa) {
#pragma unroll 1
        for (int base = s0[aa] + 8; base < s1[aa]; base += 8) {
          const int nb = s1[aa] - base;
#pragma unroll
          for (int i = 0; i < 8; ++i) {
            if (i < nb) {
              int dloc = sdst[base + i] - molbase;
              float hvv = Hf[dloc * 68 + lane];
#pragma unroll
              for (int k = 0; k < 8; ++k)
                t[aa][k] = fmaf(sbf[(size_t)(base + i) * 8 + k], hvv, t[aa][k]);
              t[aa][8] += hvv;
            }
          }
        }
      }
#pragma unroll
      for (int aa = 0; aa < 4; ++aa) {
        const int row = wv * 16 + g * 4 + aa;
#pragma unroll
        for (int k = 0; k < 9; ++k) Tb[row * 584 + k * 64 + lane] = bf16bits(t[aa][k]);
      }
    }

    // ---- Phase B: MFMA agg[i][atom]; loop i-chunks (NOT unrolled) ----
    const int tb_base = atomg * 584 + ((lane >> 4) << 3);
#pragma unroll 1
    for (int ic = 0; ic < 4; ++ic) {
      f32x4 acc = {0.f, 0.f, 0.f, 0.f};
#pragma unroll 3
      for (int ks = 0; ks < 18; ++ks) {
        bfrag8 af = KrA8[(ic * 18 + ks) * 64 + lane];
        bfrag8 bfr = *reinterpret_cast<const bfrag8*>(&Tb[tb_base + ks * 32]);
        acc = __builtin_amdgcn_mfma_f32_16x16x32_bf16(af, bfr, acc, 0, 0, 0);
      }
#pragma unroll
      for (int reg = 0; reg < 4; ++reg) {
        const int ii = ic * 16 + ((lane >> 4) << 2) + reg;
        const unsigned short hi = bf16bits(acc[reg]);
        Xh[atomg * 136 + ii] = hi;                 // own-wave atoms only
        Xl[atomg * 136 + ii] = bf16bits(acc[reg] - bf16val(hi));
      }
    }
    __syncthreads();   // all Tb reads done before AHa (alias) writes

    // ---- Phase C: GRU matvec via MFMA; loop i-chunks (NOT unrolled) ----
#pragma unroll 1
    for (int ic = 0; ic < 4; ++ic) {
      f32x4 g0 = {0,0,0,0}, g1 = {0,0,0,0}, g2 = {0,0,0,0};
      f32x4 g3 = {0,0,0,0}, g4 = {0,0,0,0}, g5 = {0,0,0,0};
      f32x4* gptr[6] = {&g0, &g1, &g2, &g3, &g4, &g5};
#pragma unroll
      for (int q = 0; q < 6; ++q) {
        const int s = q / 3;
        f32x4 g = *gptr[q];
#pragma unroll
        for (int ks = 0; ks < 2; ++ks) {
          const int fidx = ((ic * 6 + q) * 2 + ks) * 64 + lane;
          bfrag8 Ah = Wh8[fidx];
          bfrag8 Al = Wl8[fidx];
          const int xoff = atomg * 136 + (s * 2 + ks) * 32 + ((lane >> 4) << 3);
          bfrag8 Bh = *reinterpret_cast<const bfrag8*>(&Xh[xoff]);
          bfrag8 Bl = *reinterpret_cast<const bfrag8*>(&Xl[xoff]);
          g = __builtin_amdgcn_mfma_f32_16x16x32_bf16(Ah, Bh, g, 0, 0, 0);
          g = __builtin_amdgcn_mfma_f32_16x16x32_bf16(Ah, Bl, g, 0, 0, 0);
          g = __builtin_amdgcn_mfma_f32_16x16x32_bf16(Al, Bh, g, 0, 0, 0);
        }
        *gptr[q] = g;
      }
      const int ib = ic * 16 + ((lane >> 4) << 2);
      const float4 bir4 = *reinterpret_cast<const float4*>(&bih[ib]);
      const float4 biz4 = *reinterpret_cast<const float4*>(&bih[64 + ib]);
      const float4 bin4 = *reinterpret_cast<const float4*>(&bih[128 + ib]);
      const float4 bhr4 = *reinterpret_cast<const float4*>(&bhh[ib]);
      const float4 bhz4 = *reinterpret_cast<const float4*>(&bhh[64 + ib]);
      const float4 bhn4 = *reinterpret_cast<const float4*>(&bhh[128 + ib]);
      const float birA[4] = {bir4.x, bir4.y, bir4.z, bir4.w};
      const float bizA[4] = {biz4.x, biz4.y, biz4.z, biz4.w};
      const float binA[4] = {bin4.x, bin4.y, bin4.z, bin4.w};
      const float bhrA[4] = {bhr4.x, bhr4.y, bhr4.z, bhr4.w};
      const float bhzA[4] = {bhz4.x, bhz4.y, bhz4.z, bhz4.w};
      const float bhnA[4] = {bhn4.x, bhn4.y, bhn4.z, bhn4.w};
#pragma unroll
      for (int reg = 0; reg < 4; ++reg) {
        const int i = ib + reg;
        const float r = sigmoidf_(g0[reg] + birA[reg] + g3[reg] + bhrA[reg]);
        const float z = sigmoidf_(g1[reg] + bizA[reg] + g4[reg] + bhzA[reg]);
        const float nn = tanhf(g2[reg] + binA[reg] + r * (g5[reg] + bhnA[reg]));
        const float hold = Hf[atomg * 68 + i];
        AHa[atomg * 68 + i] = (1.0f - z) * nn + z * hold;
      }
    }

    // ---- copy: new h -> Hf + Xh/Xl h-part (own atoms; wave-internal LDS) ----
#pragma unroll 1
    for (int aa = 0; aa < 16; ++aa) {
      const int a = wv * 16 + aa;
      const float v = AHa[a * 68 + lane];
      Hf[a * 68 + lane] = v;
      const unsigned short hi = bf16bits(v);
      Xh[a * 136 + 64 + lane] = hi;
      Xl[a * 136 + 64 + lane] = bf16bits(v - bf16val(hi));
    }
    __syncthreads();   // all Hf updated before next step's gather / final write
  }

  // ---- final h to global ----
#pragma unroll 1
  for (int aa = 0; aa < 16; ++aa) {
    const int a = wv * 16 + aa;
    h_out[(molbase + a) * 64 + lane] = Hf[a * 68 + lane];
  }
}

// ============ fused per-molecule: QKV (MFMA) + attention + out_proj (MFMA)
//              + residual + LN1.  1 block = 1 molecule = 64 atoms. ============
__global__ __launch_bounds__(256, 1) void k_mol(
    const float* __restrict__ h,
    const unsigned short* __restrict__ PQh, const unsigned short* __restrict__ PQl,
    const unsigned short* __restrict__ POh, const unsigned short* __restrict__ POl,
    const float* __restrict__ ipb, const float* __restrict__ opb,
    const float* __restrict__ l1g, const float* __restrict__ l1b,
    float* __restrict__ y1) {
  __shared__ __align__(16) float Hf[64 * 65];             // 16,640 B
  __shared__ __align__(16) unsigned short Xh[64 * 72];    //  9,216 B
  __shared__ __align__(16) unsigned short Xl[64 * 72];    //  9,216 B
  __shared__ __align__(16) float QKVs[192 * 65];          // 49,920 B
  __shared__ __align__(16) unsigned short AOh[64 * 72];   //  9,216 B
  __shared__ __align__(16) unsigned short AOl[64 * 72];   //  9,216 B
  __shared__ __align__(16) float Of[64 * 65];             // 16,640 B
  __shared__ int vd[64];
  const int tid = threadIdx.x, lane = tid & 63, wv = tid >> 6;
  const int mol = blockIdx.x;

  for (int aa = 0; aa < 16; ++aa) {
    const int a = wv * 16 + aa;
    const float v = h[(mol * 64 + a) * 64 + lane];
    Hf[a * 65 + lane] = v;
    const unsigned short hi = bf16bits(v);
    Xh[a * 72 + lane] = hi;
    Xl[a * 72 + lane] = bf16bits(v - bf16val(hi));
    int nz = __any(v != 0.0f);
    if (lane == 0) vd[a] = nz;
  }
  __syncthreads();

  const bfrag8* PQh8 = reinterpret_cast<const bfrag8*>(PQh);
  const bfrag8* PQl8 = reinterpret_cast<const bfrag8*>(PQl);
  const int xoff_b = (wv * 16 + (lane & 15)) * 72 + ((lane >> 4) << 3);
#pragma unroll 3
  for (int tile = 0; tile < 12; ++tile) {
    f32x4 acc = {0.f, 0.f, 0.f, 0.f};
#pragma unroll
    for (int ks = 0; ks < 2; ++ks) {
      const int fidx = (tile * 2 + ks) * 64 + lane;
      bfrag8 Ah = PQh8[fidx];
      bfrag8 Al = PQl8[fidx];
      bfrag8 Bh = *reinterpret_cast<const bfrag8*>(&Xh[xoff_b + ks * 32]);
      bfrag8 Bl = *reinterpret_cast<const bfrag8*>(&Xl[xoff_b + ks * 32]);
      acc = __builtin_amdgcn_mfma_f32_16x16x32_bf16(Ah, Bh, acc, 0, 0, 0);
      acc = __builtin_amdgcn_mfma_f32_16x16x32_bf16(Ah, Bl, acc, 0, 0, 0);
      acc = __builtin_amdgcn_mfma_f32_16x16x32_bf16(Al, Bh, acc, 0, 0, 0);
    }
#pragma unroll
    for (int reg = 0; reg < 4; ++reg) {
      const int row = tile * 16 + ((lane >> 4) << 2) + reg;
      QKVs[row * 65 + wv * 16 + (lane & 15)] = acc[reg] + ipb[row];
    }
  }
  __syncthreads();

#pragma unroll
  for (int hp = 0; hp < 2; ++hp) {
    const int hh = wv * 2 + hp;
    float q[8];
#pragma unroll
    for (int j = 0; j < 8; ++j) q[j] = QKVs[(hh * 8 + j) * 65 + lane];
    float m = -3.0e38f, l = 0.f, o[8] = {0,0,0,0,0,0,0,0};
    for (int t = 0; t < 64; ++t) {
      float s = 0.f;
#pragma unroll
      for (int j = 0; j < 8; ++j) s += q[j] * QKVs[(64 + hh * 8 + j) * 65 + t];
      s *= 0.35355339059327373f;
      s = vd[t] ? s : -1.0e9f;
      float mn = fmaxf(m, s);
      float c = expf(m - mn);
      float p = expf(s - mn);
      l = l * c + p;
#pragma unroll
      for (int j = 0; j < 8; ++j) o[j] = o[j] * c + p * QKVs[(128 + hh * 8 + j) * 65 + t];
      m = mn;
    }
    const float inv = 1.0f / l;
#pragma unroll
    for (int j = 0; j < 8; ++j) {
      const float v = o[j] * inv;
      const unsigned short hi = bf16bits(v);
      AOh[lane * 72 + hh * 8 + j] = hi;
      AOl[lane * 72 + hh * 8 + j] = bf16bits(v - bf16val(hi));
    }
  }
  __syncthreads();

  const bfrag8* POh8 = reinterpret_cast<const bfrag8*>(POh);
  const bfrag8* POl8 = reinterpret_cast<const bfrag8*>(POl);
  const int aoff_b = (wv * 16 + (lane & 15)) * 72 + ((lane >> 4) << 3);
#pragma unroll
  for (int tile = 0; tile < 4; ++tile) {
    f32x4 acc = {0.f, 0.f, 0.f, 0.f};
#pragma unroll
    for (int ks = 0; ks < 2; ++ks) {
      const int fidx = (tile * 2 + ks) * 64 + lane;
      bfrag8 Ah = POh8[fidx];
      bfrag8 Al = POl8[fidx];
      bfrag8 Bh = *reinterpret_cast<const bfrag8*>(&AOh[aoff_b + ks * 32]);
      bfrag8 Bl = *reinterpret_cast<const bfrag8*>(&AOl[aoff_b + ks * 32]);
      acc = __builtin_amdgcn_mfma_f32_16x16x32_bf16(Ah, Bh, acc, 0, 0, 0);
      acc = __builtin_amdgcn_mfma_f32_16x16x32_bf16(Ah, Bl, acc, 0, 0, 0);
      acc = __builtin_amdgcn_mfma_f32_16x16x32_bf16(Al, Bh, acc, 0, 0, 0);
    }
#pragma unroll
    for (int reg = 0; reg < 4; ++reg) {
      const int dim = tile * 16 + ((lane >> 4) << 2) + reg;
      Of[(wv * 16 + (lane & 15)) * 65 + dim] = acc[reg] + opb[dim];
    }
  }
  __syncthreads();

  const float gg = l1g[lane], bbb = l1b[lane];
  for (int aa = 0; aa < 16; ++aa) {
    const int a = wv * 16 + aa;
    float val = Hf[a * 65 + lane] + Of[a * 65 + lane];
    float s1 = val, s2 = val * val;
#pragma unroll
    for (int mm = 1; mm < 64; mm <<= 1) {
      s1 += __shfl_xor(s1, mm, 64);
      s2 += __shfl_xor(s2, mm, 64);
    }
    float mu = s1 * 0.015625f;
    float var = s2 * 0.015625f - mu * mu;
    y1[(mol * 64 + a) * 64 + lane] = (val - mu) * rsqrtf(var + 1e-5f) * gg + bbb;
  }
}

// ============ FFN via MFMA (split-bf16 3-product) + residual + LN2 ============
__global__ __launch_bounds__(256, 3) void k_ffn(
    const float* __restrict__ y1,
    const unsigned short* __restrict__ W1h, const unsigned short* __restrict__ W1l,
    const unsigned short* __restrict__ W2h, const unsigned short* __restrict__ W2l,
    const float* __restrict__ b1, const float* __restrict__ b2,
    const float* __restrict__ g, const float* __restrict__ bb,
    float* __restrict__ y2) {
  __shared__ __align__(16) unsigned short Xh[16 * 72];
  __shared__ __align__(16) unsigned short Xl[16 * 72];
  __shared__ __align__(16) unsigned short Hh[16 * 520];
  __shared__ __align__(16) unsigned short Hl[16 * 520];
  __shared__ __align__(16) float Y1f[16 * 68];
  __shared__ __align__(16) float Of[16 * 68];
  const int tid = threadIdx.x, lane = tid & 63, wv = tid >> 6;
  const int ablk = blockIdx.x * 16;

#pragma unroll
  for (int aa = 0; aa < 4; ++aa) {
    const int a = wv * 4 + aa;
    const float v = y1[(ablk + a) * 64 + lane];
    Y1f[a * 68 + lane] = v;
    const unsigned short hi = bf16bits(v);
    Xh[a * 72 + lane] = hi;
    Xl[a * 72 + lane] = bf16bits(v - bf16val(hi));
  }
  __syncthreads();

  const bfrag8* W1h8 = reinterpret_cast<const bfrag8*>(W1h);
  const bfrag8* W1l8 = reinterpret_cast<const bfrag8*>(W1l);
  const int xoff_base = (lane & 15) * 72 + ((lane >> 4) << 3);
#pragma unroll 2
  for (int t = 0; t < 8; ++t) {
    f32x4 acc = {0.f, 0.f, 0.f, 0.f};
    const int tile = wv * 8 + t;
#pragma unroll
    for (int ks = 0; ks < 2; ++ks) {
      const int fidx = (tile * 2 + ks) * 64 + lane;
      bfrag8 Ah = W1h8[fidx];
      bfrag8 Al = W1l8[fidx];
      bfrag8 Bh = *reinterpret_cast<const bfrag8*>(&Xh[xoff_base + ks * 32]);
      bfrag8 Bl = *reinterpret_cast<const bfrag8*>(&Xl[xoff_base + ks * 32]);
      acc = __builtin_amdgcn_mfma_f32_16x16x32_bf16(Ah, Bh, acc, 0, 0, 0);
      acc = __builtin_amdgcn_mfma_f32_16x16x32_bf16(Ah, Bl, acc, 0, 0, 0);
      acc = __builtin_amdgcn_mfma_f32_16x16x32_bf16(Al, Bh, acc, 0, 0, 0);
    }
#pragma unroll
    for (int reg = 0; reg < 4; ++reg) {
      const int hid = tile * 16 + ((lane >> 4) << 2) + reg;
      float val = fmaxf(acc[reg] + b1[hid], 0.f);
      const unsigned short hi = bf16bits(val);
      Hh[(lane & 15) * 520 + hid] = hi;
      Hl[(lane & 15) * 520 + hid] = bf16bits(val - bf16val(hi));
    }
  }
  __syncthreads();

  const bfrag8* W2h8 = reinterpret_cast<const bfrag8*>(W2h);
  const bfrag8* W2l8 = reinterpret_cast<const bfrag8*>(W2l);
  f32x4 acc2 = {0.f, 0.f, 0.f, 0.f};
  const int hoff_base = (lane & 15) * 520 + ((lane >> 4) << 3);
#pragma unroll 4
  for (int ks = 0; ks < 16; ++ks) {
    const int fidx = (wv * 16 + ks) * 64 + lane;
    bfrag8 Ah = W2h8[fidx];
    bfrag8 Al = W2l8[fidx];
    bfrag8 Bh = *reinterpret_cast<const bfrag8*>(&Hh[hoff_base + ks * 32]);
    bfrag8 Bl = *reinterpret_cast<const bfrag8*>(&Hl[hoff_base + ks * 32]);
    acc2 = __builtin_amdgcn_mfma_f32_16x16x32_bf16(Ah, Bh, acc2, 0, 0, 0);
    acc2 = __builtin_amdgcn_mfma_f32_16x16x32_bf16(Ah, Bl, acc2, 0, 0, 0);
    acc2 = __builtin_amdgcn_mfma_f32_16x16x32_bf16(Al, Bh, acc2, 0, 0, 0);
  }
#pragma unroll
  for (int reg = 0; reg < 4; ++reg) {
    const int outr = wv * 16 + ((lane >> 4) << 2) + reg;
    Of[(lane & 15) * 68 + outr] = acc2[reg] + b2[outr];
  }
  __syncthreads();

  const float gg = g[lane], bbb = bb[lane];
#pragma unroll
  for (int aa = 0; aa < 4; ++aa) {
    const int a = wv * 4 + aa;
    float val = Y1f[a * 68 + lane] + Of[a * 68 + lane];
    float s1 = val, s2 = val * val;
#pragma unroll
    for (int mm = 1; mm < 64; mm <<= 1) {
      s1 += __shfl_xor(s1, mm, 64);
      s2 += __shfl_xor(s2, mm, 64);
    }
    float mu = s1 * 0.015625f;
    float var = s2 * 0.015625f - mu * mu;
    y2[(ablk + a) * 64 + lane] = (val - mu) * rsqrtf(var + 1e-5f) * gg + bbb;
  }
}

// ============ mean-pool + readout head fused (1 block per molecule) ============
__global__ __launch_bounds__(256) void k_head(
    const float* __restrict__ y2, const float* __restrict__ d1w,
    const float* __restrict__ d1b, const float* __restrict__ d2w,
    const float* __restrict__ d2b, float* __restrict__ out) {
  const int b = blockIdx.x;
  const int tid = threadIdx.x, lane = tid & 63, wv = tid >> 6;
  __shared__ float part[4][64];
  __shared__ float p_s[64];
  __shared__ float red_s[4];
  float s = 0.f;
#pragma unroll 4
  for (int t = wv * 16; t < wv * 16 + 16; ++t) s += y2[(b * 64 + t) * 64 + lane];
  part[wv][lane] = s;
  __syncthreads();
  if (tid < 64)
    p_s[tid] = (part[0][tid] + part[1][tid] + part[2][tid] + part[3][tid]) * 0.015625f;
  __syncthreads();
  float acc = 0.f;
#pragma unroll
  for (int rep = 0; rep < 2; ++rep) {
    int c = rep * 256 + tid;
    float hvv = d1b[c];
    for (int d = 0; d < 64; ++d) hvv += p_s[d] * d1w[d * 512 + c];
    acc += fmaxf(hvv, 0.f) * d2w[c];
  }
#pragma unroll
  for (int mm = 1; mm < 64; mm <<= 1) acc += __shfl_xor(acc, mm, 64);
  if ((tid & 63) == 0) red_s[tid >> 6] = acc;
  __syncthreads();
  if (tid == 0) {
    float t = red_s[0] + red_s[1] + red_s[2] + red_s[3] + d2b[0];
    out[b] = 1.0f / (1.0f + expf(-t));
  }
}

extern "C" void kernel_launch(void* const* d_in, const int* in_sizes, int n_in,
                              void* d_out, int out_size, void* d_ws, size_t ws_size,
                              hipStream_t stream) {
  (void)in_sizes; (void)n_in; (void)out_size; (void)ws_size;
  const float* af   = (const float*)d_in[0];
  const float* bfeat= (const float*)d_in[1];
  const int*   pairs= (const int*)d_in[2];
  // d_in[3] = molecule_indicator (identity layout; unused)
  const float* kern = (const float*)d_in[4];
  const float* kbias= (const float*)d_in[5];
  const float* wih  = (const float*)d_in[6];
  const float* whh  = (const float*)d_in[7];
  const float* bih  = (const float*)d_in[8];
  const float* bhh  = (const float*)d_in[9];
  const float* ipw  = (const float*)d_in[10];
  const float* ipb  = (const float*)d_in[11];
  const float* opw  = (const float*)d_in[12];
  const float* opb  = (const float*)d_in[13];
  const float* fw1  = (const float*)d_in[14];
  const float* fb1  = (const float*)d_in[15];
  const float* fw2  = (const float*)d_in[16];
  const float* fb2  = (const float*)d_in[17];
  const float* l1g  = (const float*)d_in[18];
  const float* l1b  = (const float*)d_in[19];
  const float* l2g  = (const float*)d_in[20];
  const float* l2b  = (const float*)d_in[21];
  const float* d1w  = (const float*)d_in[22];
  const float* d1b  = (const float*)d_in[23];
  const float* d2w  = (const float*)d_in[24];
  const float* d2b  = (const float*)d_in[25];
  float* out = (float*)d_out;

  // workspace layout (floats)
  float* ws = (float*)d_ws;
  float* h      = ws;
  float* h2     = h + (size_t)NA * 64;   // (unused; kept for layout stability)
  float* qkv    = h2 + (size_t)NA * 64;  // region reused as MP scratch
  float* ao     = qkv + (size_t)NA * 192;
  float* y1     = ao + (size_t)NA * 64;
  float* y2     = y1 + (size_t)NA * 64;
  float* pooled = y2 + (size_t)NA * 64;
  int*   valid  = (int*)(pooled + 256 * 64);
  (void)ao; (void)pooled; (void)h2;

  // weight fragments AFTER base layout (ws headroom proven in round 3).
  unsigned short* W1h = (unsigned short*)(valid + NA);
  unsigned short* W1l = W1h + 32768;
  unsigned short* W2h = W1l + 32768;
  unsigned short* W2l = W2h + 32768;
  unsigned short* PQh = W2l + 32768;     // 12288
  unsigned short* PQl = PQh + 12288;
  unsigned short* POh = PQl + 12288;     // 4096
  unsigned short* POl = POh + 4096;

  // MP-loop scratch aliased into the qkv region (dead until after the loop):
  unsigned short* KrA = (unsigned short*)qkv;  // 36864 ushort
  int*   count  = (int*)(qkv + 36864);         // NA
  int*   start  = count + NA;                  // NA+1
  int*   cursor = start + NA + 1;              // NA
  int*   bsum   = cursor + NA;                 // 256
  int*   sdst   = bsum + 256;                  // NE + 8 pad
  float* sbf    = (float*)(sdst + NE + 8);     // NE*8 + 64 pad
  unsigned short* Wh = (unsigned short*)(sbf + (size_t)NE * 8 + 64);   // 24576 ushort
  unsigned short* Wl = Wh + 24576;                                     // 24576 ushort

  k_init_prep<<<NA * 64 / 256, 256, 0, stream>>>(
      af, h, count, kern, kbias, wih, whh, fw1, fw2, ipw, opw,
      KrA, Wh, Wl, W1h, W1l, W2h, W2l, PQh, PQl, POh, POl);
  k_count<<<NE / 256, 256, 0, stream>>>(pairs, count);
  k_scan1<<<64, 256, 0, stream>>>(count, bsum);
  k_scan2<<<64, 256, 0, stream>>>(count, bsum, start, cursor);
  k_place<<<NE / 256, 256, 0, stream>>>(pairs, cursor, bfeat, sdst, sbf);

  // all 4 MP steps in one launch (edges are intra-molecule)
  k_mp<<<256, 256, 0, stream>>>(h, start, sdst, sbf, KrA, Wh, Wl, bih, bhh, h);

  k_mol<<<256, 256, 0, stream>>>(h, PQh, PQl, POh, POl, ipb, opb, l1g, l1b, y1);
  k_ffn<<<NA / 16, 256, 0, stream>>>(y1, W1h, W1l, W2h, W2l, fb1, fb2, l2g, l2b, y2);
  k_head<<<256, 256, 0, stream>>>(y2, d1w, d1b, d2w, d2b, out);
}

// Round 20
// 153.752 us; speedup vs baseline: 1.7289x; 1.7289x over previous
//
#include <hip/hip_runtime.h>
#include <hip/hip_bf16.h>
#include <math.h>

#define NA 16384
#define NE 65536
#define AD 29

typedef __attribute__((ext_vector_type(8))) short bfrag8;
typedef __attribute__((ext_vector_type(4))) float f32x4;

__device__ __forceinline__ float sigmoidf_(float x) { return 1.0f / (1.0f + expf(-x)); }
__device__ __forceinline__ unsigned short bf16bits(float x) {
  __hip_bfloat16 hb = __float2bfloat16(x);
  return *reinterpret_cast<unsigned short*>(&hb);
}
__device__ __forceinline__ float bf16val(unsigned short u) {
  unsigned int b = ((unsigned int)u) << 16;
  return __uint_as_float(b);
}

// ============ init h + zero count + ALL weight-fragment preps (one kernel) ====
__global__ void k_init_prep(
    const float* __restrict__ af, float* __restrict__ h, int* __restrict__ count,
    const float* __restrict__ kern, const float* __restrict__ kbias,
    const float* __restrict__ wih, const float* __restrict__ whh,
    const float* __restrict__ w1, const float* __restrict__ w2,
    const float* __restrict__ ipw, const float* __restrict__ opw,
    unsigned short* __restrict__ KrA,
    unsigned short* __restrict__ Wh, unsigned short* __restrict__ Wl,
    unsigned short* __restrict__ W1h, unsigned short* __restrict__ W1l,
    unsigned short* __restrict__ W2h, unsigned short* __restrict__ W2l,
    unsigned short* __restrict__ PQh, unsigned short* __restrict__ PQl,
    unsigned short* __restrict__ POh, unsigned short* __restrict__ POl) {
  int idx0 = blockIdx.x * 256 + threadIdx.x;
  if (idx0 >= NA * 64) return;
  if (idx0 < NA) count[idx0] = 0;
  {
    int a = idx0 >> 6, d = idx0 & 63;
    h[idx0] = (d < AD) ? af[a * AD + d] : 0.0f;
  }
  if (idx0 < 36864) {                     // KrA (message kernel, bf16 single)
    int idx = idx0;
    int r = idx & 7;
    int lane = (idx >> 3) & 63;
    int tmp2 = idx >> 9;                  // w*18 + ks
    int ks = tmp2 % 18, w = tmp2 / 18;
    int i = w * 16 + (lane & 15);
    int kj = ks * 32 + ((lane >> 4) << 3) + r;
    int k9 = kj >> 6, j = kj & 63;
    float v = (k9 < 8) ? kern[k9 * 4096 + i * 64 + j] : kbias[i * 64 + j];
    KrA[idx] = bf16bits(v);
  } else if (idx0 < 61440) {              // GRU weights hi/lo
    int idx = idx0 - 36864;
    int r = idx & 7;
    int lane = (idx >> 3) & 63;
    int t2 = idx >> 9;
    int ks = t2 & 1;
    int t3 = t2 >> 1;
    int q = t3 % 6, w = t3 / 6;
    int s = q / 3, g = q % 3;
    int R = g * 64 + w * 16 + (lane & 15);
    int kk = ks * 32 + ((lane >> 4) << 3) + r;
    float v = (s == 0) ? wih[R * 64 + kk] : whh[R * 64 + kk];
    unsigned short hi = bf16bits(v);
    Wh[idx] = hi;
    Wl[idx] = bf16bits(v - bf16val(hi));
  } else if (idx0 < 126976) {             // FFN weights hi/lo
    int idx = idx0 - 61440;
    int r = idx & 7;
    int lane = (idx >> 3) & 63;
    int rest = (idx >> 9) & 63;
    if (idx < 32768) {                    // W1
      int tile = rest >> 1, ks = rest & 1;
      int hid = tile * 16 + (lane & 15);
      int kk = ks * 32 + ((lane >> 4) << 3) + r;
      float v = w1[kk * 512 + hid];
      unsigned short hi = bf16bits(v);
      W1h[idx] = hi;
      W1l[idx] = bf16bits(v - bf16val(hi));
    } else {                              // W2
      int i2 = idx - 32768;
      int tile = rest >> 4, ks = rest & 15;
      int outr = tile * 16 + (lane & 15);
      int kk = ks * 32 + ((lane >> 4) << 3) + r;
      float v = w2[kk * 64 + outr];
      unsigned short hi = bf16bits(v);
      W2h[i2] = hi;
      W2l[i2] = bf16bits(v - bf16val(hi));
    }
  } else if (idx0 < 143360) {             // attn in_proj / out_proj hi/lo
    int i = idx0 - 126976;
    if (i < 12288) {                      // ipw: 12 tiles x 2 ksteps
      int r = i & 7;
      int lane = (i >> 3) & 63;
      int rest = i >> 9;                  // 0..23
      int t = rest >> 1, ks = rest & 1;
      int R = t * 16 + (lane & 15);
      int kk = ks * 32 + ((lane >> 4) << 3) + r;
      float v = ipw[R * 64 + kk];
      unsigned short hi = bf16bits(v);
      PQh[i] = hi;
      PQl[i] = bf16bits(v - bf16val(hi));
    } else {                              // opw: 4 tiles x 2 ksteps
      int i2 = i - 12288;
      int r = i2 & 7;
      int lane = (i2 >> 3) & 63;
      int rest = i2 >> 9;                 // 0..7
      int t = rest >> 1, ks = rest & 1;
      int R = t * 16 + (lane & 15);
      int kk = ks * 32 + ((lane >> 4) << 3) + r;
      float v = opw[R * 64 + kk];
      unsigned short hi = bf16bits(v);
      POh[i2] = hi;
      POl[i2] = bf16bits(v - bf16val(hi));
    }
  }
}

// ============ edge bucketing by src (once per call; counting sort) ============
__global__ void k_count(const int* __restrict__ pairs, int* __restrict__ count) {
  int e = blockIdx.x * 256 + threadIdx.x;
  if (e >= NE) return;
  atomicAdd(&count[pairs[2 * e]], 1);
}
__global__ void k_scan1(const int* __restrict__ count, int* __restrict__ bsum) {
  __shared__ int red[256];
  int b = blockIdx.x, t = threadIdx.x;
  red[t] = count[b * 256 + t];
  __syncthreads();
  for (int s = 128; s > 0; s >>= 1) { if (t < s) red[t] += red[t + s]; __syncthreads(); }
  if (t == 0) bsum[b] = red[0];
}
__global__ void k_scan2(const int* __restrict__ count, const int* __restrict__ bsum,
                        int* __restrict__ start, int* __restrict__ cursor) {
  __shared__ int sc[256];
  __shared__ int basev;
  int b = blockIdx.x, t = threadIdx.x;
  if (t < 64) {
    int v = (t < b) ? bsum[t] : 0;
#pragma unroll
    for (int off = 1; off < 64; off <<= 1) v += __shfl_xor(v, off, 64);
    if (t == 0) basev = v;
  }
  int v = count[b * 256 + t];
  sc[t] = v;
  __syncthreads();
  for (int off = 1; off < 256; off <<= 1) {
    int add = (t >= off) ? sc[t - off] : 0;
    __syncthreads();
    sc[t] += add;
    __syncthreads();
  }
  int excl = sc[t] - v + basev;
  start[b * 256 + t] = excl;
  cursor[b * 256 + t] = excl;
  if (b * 256 + t == NA - 1) start[NA] = excl + v;   // sentinel = NE
}
// place + payload reorder fused: write sorted dst + bond features directly.
__global__ void k_place(const int* __restrict__ pairs, int* __restrict__ cursor,
                        const float* __restrict__ bf, int* __restrict__ sdst,
                        float* __restrict__ sbf) {
  int e = blockIdx.x * 256 + threadIdx.x;
  if (e >= NE) return;
  int src = pairs[2 * e], dst = pairs[2 * e + 1];
  int pos = atomicAdd(&cursor[src], 1);
  sdst[pos] = dst;
  const float4* b4 = reinterpret_cast<const float4*>(&bf[e * 8]);
  float4* s4 = reinterpret_cast<float4*>(&sbf[(size_t)pos * 8]);
  s4[0] = b4[0];
  s4[1] = b4[1];
}

// ============ fused message + GRU step, fully MFMA'd dense parts ============
// (round-17/19 lessons: 4-step mega-fusion fails twice — 256-VGPR spill when
//  unrolled, 1-wave/SIMD latency exposure when not. This 16-atom one-step
//  structure at 5 blocks/CU (20 waves/CU) is the proven configuration.)
#define MW 4
#define MAW 4
__global__ __launch_bounds__(256, 5) void k_msg(
    const float* __restrict__ h_in, const int* __restrict__ start,
    const int* __restrict__ sdst, const float* __restrict__ sbf,
    const unsigned short* __restrict__ KrA,
    const unsigned short* __restrict__ Wh, const unsigned short* __restrict__ Wl,
    const float* __restrict__ bih, const float* __restrict__ bhh,
    float* __restrict__ h_out) {
  __shared__ __align__(16) unsigned short Tb[16 * 584];   // 18,688 B (AHa aliased)
  __shared__ __align__(16) unsigned short Xh[16 * 136];   // 4,352 B
  __shared__ __align__(16) unsigned short Xl[16 * 136];   // 4,352 B
  __shared__ __align__(16) float Hf[16 * 68];             // 4,352 B
  float* AHa = reinterpret_cast<float*>(Tb);              // alias (phase C only)
  const int tid = threadIdx.x, lane = tid & 63, wv = tid >> 6;
  const int ablk = blockIdx.x * 16;
  const int awave = ablk + wv * MAW;

  // ---- stage h (fp32 + bf16 hi/lo) ----
#pragma unroll
  for (int aa = 0; aa < MAW; ++aa) {
    const int a = wv * MAW + aa;
    const float v = h_in[(ablk + a) * 64 + lane];
    Hf[a * 68 + lane] = v;
    const unsigned short hi = bf16bits(v);
    Xh[a * 136 + 64 + lane] = hi;
    Xl[a * 136 + 64 + lane] = bf16bits(v - bf16val(hi));
  }

  // ---- Phase A: interleaved gather across the wave's 4 atoms ----
  int s0[MAW], s1[MAW];
#pragma unroll
  for (int a = 0; a < MAW; ++a) {
    s0[a] = __builtin_amdgcn_readfirstlane(start[awave + a]);
    s1[a] = __builtin_amdgcn_readfirstlane(start[awave + a + 1]);
  }
  float t[MAW][9];
#pragma unroll
  for (int a = 0; a < MAW; ++a)
#pragma unroll
    for (int k = 0; k < 9; ++k) t[a][k] = 0.f;

  float hv[MAW][8];
#pragma unroll
  for (int a = 0; a < MAW; ++a) {
    const int cnt = s1[a] - s0[a];
#pragma unroll
    for (int i = 0; i < 8; ++i) {
      hv[a][i] = 0.f;
      if (i < cnt) {                       // wave-uniform
        int d = sdst[s0[a] + i];
        hv[a][i] = h_in[d * 64 + lane];
      }
    }
  }
#pragma unroll
  for (int a = 0; a < MAW; ++a) {
    const int cnt = s1[a] - s0[a];
#pragma unroll
    for (int i = 0; i < 8; ++i) {
      if (i < cnt) {
#pragma unroll
        for (int k = 0; k < 8; ++k)
          t[a][k] = fmaf(sbf[(size_t)(s0[a] + i) * 8 + k], hv[a][i], t[a][k]);
        t[a][8] += hv[a][i];
      }
    }
  }
  // leftovers (>8 edges on an atom; ~2% of atoms)
#pragma unroll
  for (int a = 0; a < MAW; ++a) {
    for (int base = s0[a] + 8; base < s1[a]; base += 8) {
      const int nb = s1[a] - base;
      float hv2[8];
#pragma unroll
      for (int i = 0; i < 8; ++i) {
        hv2[i] = 0.f;
        if (i < nb) {
          int d = sdst[base + i];
          hv2[i] = h_in[d * 64 + lane];
        }
      }
#pragma unroll
      for (int i = 0; i < 8; ++i) {
        if (i < nb) {
#pragma unroll
          for (int k = 0; k < 8; ++k)
            t[a][k] = fmaf(sbf[(size_t)(base + i) * 8 + k], hv2[i], t[a][k]);
          t[a][8] += hv2[i];
        }
      }
    }
  }
#pragma unroll
  for (int a = 0; a < MAW; ++a) {
    const int row = wv * MAW + a;
#pragma unroll
    for (int k = 0; k < 9; ++k) Tb[row * 584 + k * 64 + lane] = bf16bits(t[a][k]);
  }
  __syncthreads();

  // ---- Phase B: MFMA  agg[i][atom] = sum_kj K[i][kj] * T[atom][kj] ----
  f32x4 acc = {0.f, 0.f, 0.f, 0.f};
  const bfrag8* KrA8 = reinterpret_cast<const bfrag8*>(KrA);
  const int tb_base = (lane & 15) * 584 + ((lane >> 4) << 3);
#pragma unroll 3
  for (int ks = 0; ks < 18; ++ks) {
    bfrag8 af = KrA8[(wv * 18 + ks) * 64 + lane];
    bfrag8 bfr = *reinterpret_cast<const bfrag8*>(&Tb[tb_base + ks * 32]);
    acc = __builtin_amdgcn_mfma_f32_16x16x32_bf16(af, bfr, acc, 0, 0, 0);
  }
#pragma unroll
  for (int reg = 0; reg < 4; ++reg) {
    const int ii = wv * 16 + ((lane >> 4) << 2) + reg;
    const unsigned short hi = bf16bits(acc[reg]);
    Xh[(lane & 15) * 136 + ii] = hi;
    Xl[(lane & 15) * 136 + ii] = bf16bits(acc[reg] - bf16val(hi));
  }
  __syncthreads();      // also separates last Tb read from AHa (alias) writes

  // ---- Phase C: GRU matvec via MFMA (3-product split-bf16) ----
  const bfrag8* Wh8 = reinterpret_cast<const bfrag8*>(Wh);
  const bfrag8* Wl8 = reinterpret_cast<const bfrag8*>(Wl);
  f32x4 g0 = {0,0,0,0}, g1 = {0,0,0,0}, g2 = {0,0,0,0};
  f32x4 g3 = {0,0,0,0}, g4 = {0,0,0,0}, g5 = {0,0,0,0};
  f32x4* gptr[6] = {&g0, &g1, &g2, &g3, &g4, &g5};
#pragma unroll
  for (int q = 0; q < 6; ++q) {
    const int s = q / 3;
    f32x4 g = *gptr[q];
#pragma unroll
    for (int ks = 0; ks < 2; ++ks) {
      const int fidx = ((wv * 6 + q) * 2 + ks) * 64 + lane;
      bfrag8 Ah = Wh8[fidx];
      bfrag8 Al = Wl8[fidx];
      const int xoff = (lane & 15) * 136 + (s * 2 + ks) * 32 + ((lane >> 4) << 3);
      bfrag8 Bh = *reinterpret_cast<const bfrag8*>(&Xh[xoff]);
      bfrag8 Bl = *reinterpret_cast<const bfrag8*>(&Xl[xoff]);
      g = __builtin_amdgcn_mfma_f32_16x16x32_bf16(Ah, Bh, g, 0, 0, 0);
      g = __builtin_amdgcn_mfma_f32_16x16x32_bf16(Ah, Bl, g, 0, 0, 0);
      g = __builtin_amdgcn_mfma_f32_16x16x32_bf16(Al, Bh, g, 0, 0, 0);
    }
    *gptr[q] = g;
  }
  // biases: per-thread reg-contiguous float4 loads (replaces LDS staging)
  const int ib = wv * 16 + ((lane >> 4) << 2);
  const float4 bir4 = *reinterpret_cast<const float4*>(&bih[ib]);
  const float4 biz4 = *reinterpret_cast<const float4*>(&bih[64 + ib]);
  const float4 bin4 = *reinterpret_cast<const float4*>(&bih[128 + ib]);
  const float4 bhr4 = *reinterpret_cast<const float4*>(&bhh[ib]);
  const float4 bhz4 = *reinterpret_cast<const float4*>(&bhh[64 + ib]);
  const float4 bhn4 = *reinterpret_cast<const float4*>(&bhh[128 + ib]);
  const float birA[4] = {bir4.x, bir4.y, bir4.z, bir4.w};
  const float bizA[4] = {biz4.x, biz4.y, biz4.z, biz4.w};
  const float binA[4] = {bin4.x, bin4.y, bin4.z, bin4.w};
  const float bhrA[4] = {bhr4.x, bhr4.y, bhr4.z, bhr4.w};
  const float bhzA[4] = {bhz4.x, bhz4.y, bhz4.z, bhz4.w};
  const float bhnA[4] = {bhn4.x, bhn4.y, bhn4.z, bhn4.w};
#pragma unroll
  for (int reg = 0; reg < 4; ++reg) {
    const int i = ib + reg;
    const int atom = lane & 15;
    const float r = sigmoidf_(g0[reg] + birA[reg] + g3[reg] + bhrA[reg]);
    const float z = sigmoidf_(g1[reg] + bizA[reg] + g4[reg] + bhzA[reg]);
    const float nn = tanhf(g2[reg] + binA[reg] + r * (g5[reg] + bhnA[reg]));
    const float hold = Hf[atom * 68 + i];
    AHa[atom * 68 + i] = (1.0f - z) * nn + z * hold;
  }
  __syncthreads();
#pragma unroll
  for (int aa = 0; aa < MAW; ++aa) {
    const int a = wv * MAW + aa;
    h_out[(ablk + a) * 64 + lane] = AHa[a * 68 + lane];
  }
}

// ============ fused per-molecule: QKV (MFMA) + attention + out_proj (MFMA)
//              + residual + LN1.  1 block = 1 molecule = 64 atoms. ============
__global__ __launch_bounds__(256, 1) void k_mol(
    const float* __restrict__ h,
    const unsigned short* __restrict__ PQh, const unsigned short* __restrict__ PQl,
    const unsigned short* __restrict__ POh, const unsigned short* __restrict__ POl,
    const float* __restrict__ ipb, const float* __restrict__ opb,
    const float* __restrict__ l1g, const float* __restrict__ l1b,
    float* __restrict__ y1) {
  __shared__ __align__(16) float Hf[64 * 65];             // 16,640 B
  __shared__ __align__(16) unsigned short Xh[64 * 72];    //  9,216 B
  __shared__ __align__(16) unsigned short Xl[64 * 72];    //  9,216 B
  __shared__ __align__(16) float QKVs[192 * 65];          // 49,920 B
  __shared__ __align__(16) unsigned short AOh[64 * 72];   //  9,216 B
  __shared__ __align__(16) unsigned short AOl[64 * 72];   //  9,216 B
  __shared__ __align__(16) float Of[64 * 65];             // 16,640 B
  __shared__ int vd[64];
  const int tid = threadIdx.x, lane = tid & 63, wv = tid >> 6;
  const int mol = blockIdx.x;

  for (int aa = 0; aa < 16; ++aa) {
    const int a = wv * 16 + aa;
    const float v = h[(mol * 64 + a) * 64 + lane];
    Hf[a * 65 + lane] = v;
    const unsigned short hi = bf16bits(v);
    Xh[a * 72 + lane] = hi;
    Xl[a * 72 + lane] = bf16bits(v - bf16val(hi));
    int nz = __any(v != 0.0f);
    if (lane == 0) vd[a] = nz;
  }
  __syncthreads();

  const bfrag8* PQh8 = reinterpret_cast<const bfrag8*>(PQh);
  const bfrag8* PQl8 = reinterpret_cast<const bfrag8*>(PQl);
  const int xoff_b = (wv * 16 + (lane & 15)) * 72 + ((lane >> 4) << 3);
#pragma unroll 3
  for (int tile = 0; tile < 12; ++tile) {
    f32x4 acc = {0.f, 0.f, 0.f, 0.f};
#pragma unroll
    for (int ks = 0; ks < 2; ++ks) {
      const int fidx = (tile * 2 + ks) * 64 + lane;
      bfrag8 Ah = PQh8[fidx];
      bfrag8 Al = PQl8[fidx];
      bfrag8 Bh = *reinterpret_cast<const bfrag8*>(&Xh[xoff_b + ks * 32]);
      bfrag8 Bl = *reinterpret_cast<const bfrag8*>(&Xl[xoff_b + ks * 32]);
      acc = __builtin_amdgcn_mfma_f32_16x16x32_bf16(Ah, Bh, acc, 0, 0, 0);
      acc = __builtin_amdgcn_mfma_f32_16x16x32_bf16(Ah, Bl, acc, 0, 0, 0);
      acc = __builtin_amdgcn_mfma_f32_16x16x32_bf16(Al, Bh, acc, 0, 0, 0);
    }
#pragma unroll
    for (int reg = 0; reg < 4; ++reg) {
      const int row = tile * 16 + ((lane >> 4) << 2) + reg;
      QKVs[row * 65 + wv * 16 + (lane & 15)] = acc[reg] + ipb[row];
    }
  }
  __syncthreads();

#pragma unroll
  for (int hp = 0; hp < 2; ++hp) {
    const int hh = wv * 2 + hp;
    float q[8];
#pragma unroll
    for (int j = 0; j < 8; ++j) q[j] = QKVs[(hh * 8 + j) * 65 + lane];
    float m = -3.0e38f, l = 0.f, o[8] = {0,0,0,0,0,0,0,0};
    for (int t = 0; t < 64; ++t) {
      float s = 0.f;
#pragma unroll
      for (int j = 0; j < 8; ++j) s += q[j] * QKVs[(64 + hh * 8 + j) * 65 + t];
      s *= 0.35355339059327373f;
      s = vd[t] ? s : -1.0e9f;
      float mn = fmaxf(m, s);
      float c = expf(m - mn);
      float p = expf(s - mn);
      l = l * c + p;
#pragma unroll
      for (int j = 0; j < 8; ++j) o[j] = o[j] * c + p * QKVs[(128 + hh * 8 + j) * 65 + t];
      m = mn;
    }
    const float inv = 1.0f / l;
#pragma unroll
    for (int j = 0; j < 8; ++j) {
      const float v = o[j] * inv;
      const unsigned short hi = bf16bits(v);
      AOh[lane * 72 + hh * 8 + j] = hi;
      AOl[lane * 72 + hh * 8 + j] = bf16bits(v - bf16val(hi));
    }
  }
  __syncthreads();

  const bfrag8* POh8 = reinterpret_cast<const bfrag8*>(POh);
  const bfrag8* POl8 = reinterpret_cast<const bfrag8*>(POl);
  const int aoff_b = (wv * 16 + (lane & 15)) * 72 + ((lane >> 4) << 3);
#pragma unroll
  for (int tile = 0; tile < 4; ++tile) {
    f32x4 acc = {0.f, 0.f, 0.f, 0.f};
#pragma unroll
    for (int ks = 0; ks < 2; ++ks) {
      const int fidx = (tile * 2 + ks) * 64 + lane;
      bfrag8 Ah = POh8[fidx];
      bfrag8 Al = POl8[fidx];
      bfrag8 Bh = *reinterpret_cast<const bfrag8*>(&AOh[aoff_b + ks * 32]);
      bfrag8 Bl = *reinterpret_cast<const bfrag8*>(&AOl[aoff_b + ks * 32]);
      acc = __builtin_amdgcn_mfma_f32_16x16x32_bf16(Ah, Bh, acc, 0, 0, 0);
      acc = __builtin_amdgcn_mfma_f32_16x16x32_bf16(Ah, Bl, acc, 0, 0, 0);
      acc = __builtin_amdgcn_mfma_f32_16x16x32_bf16(Al, Bh, acc, 0, 0, 0);
    }
#pragma unroll
    for (int reg = 0; reg < 4; ++reg) {
      const int dim = tile * 16 + ((lane >> 4) << 2) + reg;
      Of[(wv * 16 + (lane & 15)) * 65 + dim] = acc[reg] + opb[dim];
    }
  }
  __syncthreads();

  const float gg = l1g[lane], bbb = l1b[lane];
  for (int aa = 0; aa < 16; ++aa) {
    const int a = wv * 16 + aa;
    float val = Hf[a * 65 + lane] + Of[a * 65 + lane];
    float s1 = val, s2 = val * val;
#pragma unroll
    for (int mm = 1; mm < 64; mm <<= 1) {
      s1 += __shfl_xor(s1, mm, 64);
      s2 += __shfl_xor(s2, mm, 64);
    }
    float mu = s1 * 0.015625f;
    float var = s2 * 0.015625f - mu * mu;
    y1[(mol * 64 + a) * 64 + lane] = (val - mu) * rsqrtf(var + 1e-5f) * gg + bbb;
  }
}

// ============ FFN via MFMA (split-bf16 3-product) + residual + LN2 ============
__global__ __launch_bounds__(256, 3) void k_ffn(
    const float* __restrict__ y1,
    const unsigned short* __restrict__ W1h, const unsigned short* __restrict__ W1l,
    const unsigned short* __restrict__ W2h, const unsigned short* __restrict__ W2l,
    const float* __restrict__ b1, const float* __restrict__ b2,
    const float* __restrict__ g, const float* __restrict__ bb,
    float* __restrict__ y2) {
  __shared__ __align__(16) unsigned short Xh[16 * 72];
  __shared__ __align__(16) unsigned short Xl[16 * 72];
  __shared__ __align__(16) unsigned short Hh[16 * 520];
  __shared__ __align__(16) unsigned short Hl[16 * 520];
  __shared__ __align__(16) float Y1f[16 * 68];
  __shared__ __align__(16) float Of[16 * 68];
  const int tid = threadIdx.x, lane = tid & 63, wv = tid >> 6;
  const int ablk = blockIdx.x * 16;

#pragma unroll
  for (int aa = 0; aa < 4; ++aa) {
    const int a = wv * 4 + aa;
    const float v = y1[(ablk + a) * 64 + lane];
    Y1f[a * 68 + lane] = v;
    const unsigned short hi = bf16bits(v);
    Xh[a * 72 + lane] = hi;
    Xl[a * 72 + lane] = bf16bits(v - bf16val(hi));
  }
  __syncthreads();

  const bfrag8* W1h8 = reinterpret_cast<const bfrag8*>(W1h);
  const bfrag8* W1l8 = reinterpret_cast<const bfrag8*>(W1l);
  const int xoff_base = (lane & 15) * 72 + ((lane >> 4) << 3);
#pragma unroll 2
  for (int t = 0; t < 8; ++t) {
    f32x4 acc = {0.f, 0.f, 0.f, 0.f};
    const int tile = wv * 8 + t;
#pragma unroll
    for (int ks = 0; ks < 2; ++ks) {
      const int fidx = (tile * 2 + ks) * 64 + lane;
      bfrag8 Ah = W1h8[fidx];
      bfrag8 Al = W1l8[fidx];
      bfrag8 Bh = *reinterpret_cast<const bfrag8*>(&Xh[xoff_base + ks * 32]);
      bfrag8 Bl = *reinterpret_cast<const bfrag8*>(&Xl[xoff_base + ks * 32]);
      acc = __builtin_amdgcn_mfma_f32_16x16x32_bf16(Ah, Bh, acc, 0, 0, 0);
      acc = __builtin_amdgcn_mfma_f32_16x16x32_bf16(Ah, Bl, acc, 0, 0, 0);
      acc = __builtin_amdgcn_mfma_f32_16x16x32_bf16(Al, Bh, acc, 0, 0, 0);
    }
#pragma unroll
    for (int reg = 0; reg < 4; ++reg) {
      const int hid = tile * 16 + ((lane >> 4) << 2) + reg;
      float val = fmaxf(acc[reg] + b1[hid], 0.f);
      const unsigned short hi = bf16bits(val);
      Hh[(lane & 15) * 520 + hid] = hi;
      Hl[(lane & 15) * 520 + hid] = bf16bits(val - bf16val(hi));
    }
  }
  __syncthreads();

  const bfrag8* W2h8 = reinterpret_cast<const bfrag8*>(W2h);
  const bfrag8* W2l8 = reinterpret_cast<const bfrag8*>(W2l);
  f32x4 acc2 = {0.f, 0.f, 0.f, 0.f};
  const int hoff_base = (lane & 15) * 520 + ((lane >> 4) << 3);
#pragma unroll 4
  for (int ks = 0; ks < 16; ++ks) {
    const int fidx = (wv * 16 + ks) * 64 + lane;
    bfrag8 Ah = W2h8[fidx];
    bfrag8 Al = W2l8[fidx];
    bfrag8 Bh = *reinterpret_cast<const bfrag8*>(&Hh[hoff_base + ks * 32]);
    bfrag8 Bl = *reinterpret_cast<const bfrag8*>(&Hl[hoff_base + ks * 32]);
    acc2 = __builtin_amdgcn_mfma_f32_16x16x32_bf16(Ah, Bh, acc2, 0, 0, 0);
    acc2 = __builtin_amdgcn_mfma_f32_16x16x32_bf16(Ah, Bl, acc2, 0, 0, 0);
    acc2 = __builtin_amdgcn_mfma_f32_16x16x32_bf16(Al, Bh, acc2, 0, 0, 0);
  }
#pragma unroll
  for (int reg = 0; reg < 4; ++reg) {
    const int outr = wv * 16 + ((lane >> 4) << 2) + reg;
    Of[(lane & 15) * 68 + outr] = acc2[reg] + b2[outr];
  }
  __syncthreads();

  const float gg = g[lane], bbb = bb[lane];
#pragma unroll
  for (int aa = 0; aa < 4; ++aa) {
    const int a = wv * 4 + aa;
    float val = Y1f[a * 68 + lane] + Of[a * 68 + lane];
    float s1 = val, s2 = val * val;
#pragma unroll
    for (int mm = 1; mm < 64; mm <<= 1) {
      s1 += __shfl_xor(s1, mm, 64);
      s2 += __shfl_xor(s2, mm, 64);
    }
    float mu = s1 * 0.015625f;
    float var = s2 * 0.015625f - mu * mu;
    y2[(ablk + a) * 64 + lane] = (val - mu) * rsqrtf(var + 1e-5f) * gg + bbb;
  }
}

// ============ mean-pool + readout head fused (1 block per molecule) ============
__global__ __launch_bounds__(256) void k_head(
    const float* __restrict__ y2, const float* __restrict__ d1w,
    const float* __restrict__ d1b, const float* __restrict__ d2w,
    const float* __restrict__ d2b, float* __restrict__ out) {
  const int b = blockIdx.x;
  const int tid = threadIdx.x, lane = tid & 63, wv = tid >> 6;
  __shared__ float part[4][64];
  __shared__ float p_s[64];
  __shared__ float red_s[4];
  float s = 0.f;
#pragma unroll 4
  for (int t = wv * 16; t < wv * 16 + 16; ++t) s += y2[(b * 64 + t) * 64 + lane];
  part[wv][lane] = s;
  __syncthreads();
  if (tid < 64)
    p_s[tid] = (part[0][tid] + part[1][tid] + part[2][tid] + part[3][tid]) * 0.015625f;
  __syncthreads();
  float acc = 0.f;
#pragma unroll
  for (int rep = 0; rep < 2; ++rep) {
    int c = rep * 256 + tid;
    float hvv = d1b[c];
    for (int d = 0; d < 64; ++d) hvv += p_s[d] * d1w[d * 512 + c];
    acc += fmaxf(hvv, 0.f) * d2w[c];
  }
#pragma unroll
  for (int mm = 1; mm < 64; mm <<= 1) acc += __shfl_xor(acc, mm, 64);
  if ((tid & 63) == 0) red_s[tid >> 6] = acc;
  __syncthreads();
  if (tid == 0) {
    float t = red_s[0] + red_s[1] + red_s[2] + red_s[3] + d2b[0];
    out[b] = 1.0f / (1.0f + expf(-t));
  }
}

extern "C" void kernel_launch(void* const* d_in, const int* in_sizes, int n_in,
                              void* d_out, int out_size, void* d_ws, size_t ws_size,
                              hipStream_t stream) {
  (void)in_sizes; (void)n_in; (void)out_size; (void)ws_size;
  const float* af   = (const float*)d_in[0];
  const float* bfeat= (const float*)d_in[1];
  const int*   pairs= (const int*)d_in[2];
  // d_in[3] = molecule_indicator (identity layout; unused)
  const float* kern = (const float*)d_in[4];
  const float* kbias= (const float*)d_in[5];
  const float* wih  = (const float*)d_in[6];
  const float* whh  = (const float*)d_in[7];
  const float* bih  = (const float*)d_in[8];
  const float* bhh  = (const float*)d_in[9];
  const float* ipw  = (const float*)d_in[10];
  const float* ipb  = (const float*)d_in[11];
  const float* opw  = (const float*)d_in[12];
  const float* opb  = (const float*)d_in[13];
  const float* fw1  = (const float*)d_in[14];
  const float* fb1  = (const float*)d_in[15];
  const float* fw2  = (const float*)d_in[16];
  const float* fb2  = (const float*)d_in[17];
  const float* l1g  = (const float*)d_in[18];
  const float* l1b  = (const float*)d_in[19];
  const float* l2g  = (const float*)d_in[20];
  const float* l2b  = (const float*)d_in[21];
  const float* d1w  = (const float*)d_in[22];
  const float* d1b  = (const float*)d_in[23];
  const float* d2w  = (const float*)d_in[24];
  const float* d2b  = (const float*)d_in[25];
  float* out = (float*)d_out;

  // workspace layout (floats)
  float* ws = (float*)d_ws;
  float* h      = ws;                    // ping buffer (final h after 4 steps)
  float* h2     = h + (size_t)NA * 64;   // pong buffer
  float* qkv    = h2 + (size_t)NA * 64;  // region reused as MP scratch
  float* ao     = qkv + (size_t)NA * 192;
  float* y1     = ao + (size_t)NA * 64;
  float* y2     = y1 + (size_t)NA * 64;
  float* pooled = y2 + (size_t)NA * 64;
  int*   valid  = (int*)(pooled + 256 * 64);
  (void)ao; (void)pooled;

  // weight fragments AFTER base layout (ws headroom proven in round 3).
  unsigned short* W1h = (unsigned short*)(valid + NA);
  unsigned short* W1l = W1h + 32768;
  unsigned short* W2h = W1l + 32768;
  unsigned short* W2l = W2h + 32768;
  unsigned short* PQh = W2l + 32768;     // 12288
  unsigned short* PQl = PQh + 12288;
  unsigned short* POh = PQl + 12288;     // 4096
  unsigned short* POl = POh + 4096;

  // MP-loop scratch aliased into the qkv region (dead until after the loop):
  unsigned short* KrA = (unsigned short*)qkv;  // 36864 ushort
  int*   count  = (int*)(qkv + 36864);         // NA
  int*   start  = count + NA;                  // NA+1
  int*   cursor = start + NA + 1;              // NA
  int*   bsum   = cursor + NA;                 // 256
  int*   sdst   = bsum + 256;                  // NE + 8 pad
  float* sbf    = (float*)(sdst + NE + 8);     // NE*8 + 64 pad
  unsigned short* Wh = (unsigned short*)(sbf + (size_t)NE * 8 + 64);   // 24576 ushort
  unsigned short* Wl = Wh + 24576;                                     // 24576 ushort

  k_init_prep<<<NA * 64 / 256, 256, 0, stream>>>(
      af, h, count, kern, kbias, wih, whh, fw1, fw2, ipw, opw,
      KrA, Wh, Wl, W1h, W1l, W2h, W2l, PQh, PQl, POh, POl);
  k_count<<<NE / 256, 256, 0, stream>>>(pairs, count);
  k_scan1<<<64, 256, 0, stream>>>(count, bsum);
  k_scan2<<<64, 256, 0, stream>>>(count, bsum, start, cursor);
  k_place<<<NE / 256, 256, 0, stream>>>(pairs, cursor, bfeat, sdst, sbf);

  float* hin = h;
  float* hout = h2;
  for (int s = 0; s < 4; ++s) {
    k_msg<<<NA / 16, 256, 0, stream>>>(hin, start, sdst, sbf, KrA,
                                       Wh, Wl, bih, bhh, hout);
    float* tmp = hin; hin = hout; hout = tmp;
  }
  // 4 swaps -> final h is back in 'h'

  k_mol<<<256, 256, 0, stream>>>(h, PQh, PQl, POh, POl, ipb, opb, l1g, l1b, y1);
  k_ffn<<<NA / 16, 256, 0, stream>>>(y1, W1h, W1l, W2h, W2l, fb1, fb2, l2g, l2b, y2);
  k_head<<<256, 256, 0, stream>>>(y2, d1w, d1b, d2w, d2b, out);
}